// Round 2
// baseline (1609.240 us; speedup 1.0000x reference)
//
#include <hip/hip_runtime.h>
#include <hip/hip_bf16.h>

// Sparse 3D conv block (4x 27-tap convs, N=64), float32 in/out.
// Round 2: f32 dtypes + split-bf16 (emulated-f32) MFMA.
//   x = x_hi + x_lo (both bf16, exact split), product = hi*hi + hi*lo + lo*hi
//   -> ~2^-16 rel error/term, passes 1e-1 abs threshold with huge margin.
// Pre-passes: feats f32 -> hl[P][128] bf16 (into d_out as scratch);
//             W[27][64][64] f32 -> Wt[27][64][128] bf16 (k, n, i_hi||i_lo) in ws.
// Chain: split(feats)->out_hl; conv1a: out_hl->hA; conv1b: hA->out_hl (FiLM);
//        conv2a: out_hl->hA; conv2b: hA->d_out f32 (relu + feats residual).

#define N 64
#define TAPS 27
#define MT 64
#define PITCH 72   // bf16 elems per LDS row (144 B)

typedef unsigned short u16;
typedef __attribute__((ext_vector_type(8))) short short8;
typedef __attribute__((ext_vector_type(4))) float floatx4;

__device__ __forceinline__ float bf2f(u16 v) {
    union { unsigned u; float f; } c;
    c.u = ((unsigned)v) << 16;
    return c.f;
}
__device__ __forceinline__ u16 f2bf(float f) {
    __hip_bfloat16 h = __float2bfloat16(f);  // RNE
    u16 r;
    __builtin_memcpy(&r, &h, 2);
    return r;
}
__device__ __forceinline__ void split2(float x, u16& hi, u16& lo) {
    hi = f2bf(x);
    lo = f2bf(x - bf2f(hi));
}

// feats f32 [P][64] -> hl bf16 [P][128] (row = hi[0:64] || lo[64:128])
__global__ void split_feats(const float* __restrict__ x, u16* __restrict__ hl, int n) {
    int i = blockIdx.x * 256 + threadIdx.x;
    if (i >= n) return;
    int p = i >> 6, c = i & 63;
    u16 h, l;
    split2(x[i], h, l);
    hl[(size_t)p * 128 + c] = h;
    hl[(size_t)p * 128 + 64 + c] = l;
}

// W f32 [27][64][64] (k,i,j) -> Wt bf16 [27][64][128] (k, j, i_hi||i_lo)
__global__ void transpose_w(const float* __restrict__ W, u16* __restrict__ Wt) {
    const float* src = W + blockIdx.x * (N * N);
    u16* dst = Wt + blockIdx.x * (N * 128);
    int t = threadIdx.x;
#pragma unroll
    for (int m = 0; m < 16; ++m) {
        int e = t + m * 256;
        int i = e >> 6;
        int j = e & 63;
        u16 h, l;
        split2(src[e], h, l);
        dst[j * 128 + i] = h;
        dst[j * 128 + 64 + i] = l;
    }
}

// MODE: 0/2 = relu -> hl out; 1 = FiLM -> hl out; 3 = relu + residual -> f32 out
template <int MODE>
__global__ __launch_bounds__(256) void conv_k(
    const u16* __restrict__ Xhl, const u16* __restrict__ Wt,
    const float* __restrict__ bias, const int* __restrict__ nbr,
    const float* __restrict__ cond, const float* __restrict__ resid,
    u16* __restrict__ out_hl, float* __restrict__ out_f32, int P) {
    __shared__ u16 Ah[MT * PITCH];
    __shared__ u16 Al[MT * PITCH];
    __shared__ u16 Bh[N * PITCH];
    __shared__ u16 Bl[N * PITCH];
    __shared__ int Ns[MT * TAPS];

    const int tid = threadIdx.x;
    const int pbase = blockIdx.x * MT;

    for (int e = tid; e < MT * TAPS; e += 256) {
        int r = e / TAPS;
        int p = pbase + r;
        Ns[e] = (p < P) ? nbr[p * TAPS + (e - r * TAPS)] : -1;
    }

    const int wave = tid >> 6;
    const int lane = tid & 63;
    const int lm = lane & 15;   // row/col within 16x16 tile
    const int lb = lane >> 4;   // k sub-block 0..3

    const int r = tid >> 2;     // staging row 0..63
    const int q = tid & 3;      // quarter-row: q<2 -> hi plane, else lo plane

    floatx4 acc[4];
#pragma unroll
    for (int i = 0; i < 4; ++i) acc[i] = (floatx4){0.f, 0.f, 0.f, 0.f};

    __syncthreads();

    for (int k = 0; k < TAPS; ++k) {
        // ---- stage A: gathered hl rows of X (zero for missing neighbors)
        int idx = Ns[r * TAPS + k];
        const u16* wsrc = Wt + k * (N * 128) + r * 128;
#pragma unroll
        for (int c = 0; c < 4; ++c) {
            int e = q * 32 + c * 8;  // elem offset in the 128-wide hl row
            uint4 av = make_uint4(0u, 0u, 0u, 0u);
            if (idx >= 0)
                av = *reinterpret_cast<const uint4*>(Xhl + (size_t)idx * 128 + e);
            uint4 bv = *reinterpret_cast<const uint4*>(wsrc + e);
            if (e < 64) {
                *reinterpret_cast<uint4*>(&Ah[r * PITCH + e]) = av;
                *reinterpret_cast<uint4*>(&Bh[r * PITCH + e]) = bv;
            } else {
                *reinterpret_cast<uint4*>(&Al[r * PITCH + e - 64]) = av;
                *reinterpret_cast<uint4*>(&Bl[r * PITCH + e - 64]) = bv;
            }
        }
        __syncthreads();

        // ---- MFMA: wave handles rows [wave*16, wave*16+16) x all 64 cols
        short8 ah[2], al[2];
#pragma unroll
        for (int kc = 0; kc < 2; ++kc) {
            int off = (wave * 16 + lm) * PITCH + kc * 32 + lb * 8;
            ah[kc] = *reinterpret_cast<const short8*>(&Ah[off]);
            al[kc] = *reinterpret_cast<const short8*>(&Al[off]);
        }
#pragma unroll
        for (int nt = 0; nt < 4; ++nt) {
#pragma unroll
            for (int kc = 0; kc < 2; ++kc) {
                int off = (nt * 16 + lm) * PITCH + kc * 32 + lb * 8;
                short8 bh = *reinterpret_cast<const short8*>(&Bh[off]);
                short8 bl = *reinterpret_cast<const short8*>(&Bl[off]);
                acc[nt] = __builtin_amdgcn_mfma_f32_16x16x32_bf16(ah[kc], bh, acc[nt], 0, 0, 0);
                acc[nt] = __builtin_amdgcn_mfma_f32_16x16x32_bf16(ah[kc], bl, acc[nt], 0, 0, 0);
                acc[nt] = __builtin_amdgcn_mfma_f32_16x16x32_bf16(al[kc], bh, acc[nt], 0, 0, 0);
            }
        }
        __syncthreads();
    }

    // ---- epilogue: D[row=lb*4+v][col=lm] per 16x16 tile
    const int prow = pbase + wave * 16 + lb * 4;
#pragma unroll
    for (int nt = 0; nt < 4; ++nt) {
        int j = nt * 16 + lm;
        float bj = bias[j];
#pragma unroll
        for (int v = 0; v < 4; ++v) {
            int p = prow + v;
            if (p < P) {
                float o = acc[nt][v] + bj;
                if (MODE == 0 || MODE == 2) o = fmaxf(o, 0.f);
                if (MODE == 1) {
                    float be = cond[(size_t)p * (2 * N) + j];
                    float ga = cond[(size_t)p * (2 * N) + N + j];
                    o = o * be + ga;
                }
                if (MODE == 3) {
                    o = fmaxf(o, 0.f) + resid[(size_t)p * N + j];
                    out_f32[(size_t)p * N + j] = o;
                } else {
                    u16 h, l;
                    split2(o, h, l);
                    out_hl[(size_t)p * 128 + j] = h;
                    out_hl[(size_t)p * 128 + 64 + j] = l;
                }
            }
        }
    }
}

extern "C" void kernel_launch(void* const* d_in, const int* in_sizes, int n_in,
                              void* d_out, int out_size, void* d_ws, size_t ws_size,
                              hipStream_t stream) {
    const float* feats = (const float*)d_in[0];
    const float* cond  = (const float*)d_in[1];
    const float* W1a   = (const float*)d_in[2];
    const float* b1a   = (const float*)d_in[3];
    const float* W1b   = (const float*)d_in[4];
    const float* b1b   = (const float*)d_in[5];
    const float* W2a   = (const float*)d_in[6];
    const float* b2a   = (const float*)d_in[7];
    const float* W2b   = (const float*)d_in[8];
    const float* b2b   = (const float*)d_in[9];
    const int* nbr     = (const int*)d_in[10];
    float* out = (float*)d_out;
    u16* out_hl = (u16*)d_out;   // d_out doubles as hl scratch (P*128 bf16 == P*64 f32 bytes)

    const int P = in_sizes[0] / N;

    const size_t wtElems = (size_t)TAPS * N * 128;  // 221184 bf16 per conv
    u16* wt0 = (u16*)d_ws;
    u16* wt1 = wt0 + wtElems;
    u16* wt2 = wt1 + wtElems;
    u16* wt3 = wt2 + wtElems;
    u16* hA  = wt3 + wtElems;    // P*128 bf16 intermediate

    transpose_w<<<TAPS, 256, 0, stream>>>(W1a, wt0);
    transpose_w<<<TAPS, 256, 0, stream>>>(W1b, wt1);
    transpose_w<<<TAPS, 256, 0, stream>>>(W2a, wt2);
    transpose_w<<<TAPS, 256, 0, stream>>>(W2b, wt3);
    split_feats<<<(P * N + 255) / 256, 256, 0, stream>>>(feats, out_hl, P * N);

    const int blocks = (P + MT - 1) / MT;
    conv_k<0><<<blocks, 256, 0, stream>>>(out_hl, wt0, b1a, nbr, nullptr, nullptr, hA, nullptr, P);
    conv_k<1><<<blocks, 256, 0, stream>>>(hA, wt1, b1b, nbr, cond, nullptr, out_hl, nullptr, P);
    conv_k<2><<<blocks, 256, 0, stream>>>(out_hl, wt2, b2a, nbr, nullptr, nullptr, hA, nullptr, P);
    conv_k<3><<<blocks, 256, 0, stream>>>(hA, wt3, b2b, nbr, nullptr, feats, nullptr, out, P);
}